// Round 1
// baseline (5760.849 us; speedup 1.0000x reference)
//
#include <hip/hip_runtime.h>
#include <cstdint>
#include <cstddef>

#define N_NODES 100000
#define N_EDGES 1200000
#define ASIZE 256
#define HSIZE 64
#define NTYPES 4
#define NSTEPS 6
#define NGRAPH 64

static __device__ __forceinline__ float sigmoidf_(float x) { return 1.0f / (1.0f + expf(-x)); }

// ---------------- CSR build (by dst) ----------------
__global__ void k_count(const int* __restrict__ dst, int* __restrict__ deg) {
    int e = blockIdx.x * 256 + threadIdx.x;
    if (e < N_EDGES) atomicAdd(&deg[dst[e]], 1);
}

// block scans 1024 items (256 thr x 4); writes block-local exclusive prefix + block total
__global__ void k_scan1(const int* __restrict__ deg, int* __restrict__ rs, int* __restrict__ part) {
    __shared__ int sh[256];
    int t = threadIdx.x;
    int base = blockIdx.x * 1024 + t * 4;
    int v0 = (base + 0 < N_NODES) ? deg[base + 0] : 0;
    int v1 = (base + 1 < N_NODES) ? deg[base + 1] : 0;
    int v2 = (base + 2 < N_NODES) ? deg[base + 2] : 0;
    int v3 = (base + 3 < N_NODES) ? deg[base + 3] : 0;
    int s = v0 + v1 + v2 + v3;
    sh[t] = s;
    __syncthreads();
    for (int off = 1; off < 256; off <<= 1) {
        int x = (t >= off) ? sh[t - off] : 0;
        __syncthreads();
        sh[t] += x;
        __syncthreads();
    }
    int excl = sh[t] - s;  // block-local exclusive at this thread's start
    if (t == 255) part[blockIdx.x] = sh[255];
    if (base + 0 < N_NODES) rs[base + 0] = excl;
    if (base + 1 < N_NODES) rs[base + 1] = excl + v0;
    if (base + 2 < N_NODES) rs[base + 2] = excl + v0 + v1;
    if (base + 3 < N_NODES) rs[base + 3] = excl + v0 + v1 + v2;
}

__global__ void k_scan2(int* __restrict__ part, int* __restrict__ rs, int nb) {
    if (threadIdx.x == 0 && blockIdx.x == 0) {
        int run = 0;
        for (int i = 0; i < nb; ++i) { int v = part[i]; part[i] = run; run += v; }
        rs[N_NODES] = run;   // == N_EDGES
    }
}

__global__ void k_scan3(int* __restrict__ rs, const int* __restrict__ part) {
    int i = blockIdx.x * 256 + threadIdx.x;
    if (i < N_NODES) rs[i] += part[i >> 10];
}

__global__ void k_fill(const int* __restrict__ src, const int* __restrict__ dst,
                       const int* __restrict__ ety, const int* __restrict__ rs,
                       int* __restrict__ cur, int* __restrict__ colidx) {
    int e = blockIdx.x * 256 + threadIdx.x;
    if (e < N_EDGES) {
        int d = dst[e];
        int pos = rs[d] + atomicAdd(&cur[d], 1);
        colidx[pos] = ety[e] * N_NODES + src[e];  // row index into trans
    }
}

// ---------------- weight prep: transpose GRU weights to [gate][k][j] ----------------
__global__ void k_prepW(const float* __restrict__ Wi, const float* __restrict__ Wh,
                        float* __restrict__ WiT, float* __restrict__ WhT) {
    int i = blockIdx.x * 256 + threadIdx.x;  // over 3*64*64
    if (i < 3 * 64 * 64) {
        int g = i >> 12;
        int k = (i >> 6) & 63;
        int j = i & 63;
        WiT[i] = Wi[(g * 64 + j) * 64 + k];
        WhT[i] = Wh[(g * 64 + j) * 64 + k];
    }
}

__global__ void k_init(unsigned int* __restrict__ gmax, float* __restrict__ denom,
                       float* __restrict__ ro) {
    int i = blockIdx.x * 256 + threadIdx.x;
    if (i < NGRAPH * 128) ro[i] = 0.0f;
    if (i < NGRAPH) { gmax[i] = 0u; denom[i] = 0.0f; }
}

// ---------------- reduce layer: h0 = ann @ rW + rb ; h = h0 ----------------
// wave (64 lanes = 64 out cols) handles 16 nodes; K=256 in 4 chunks of 64 held in VGPRs
__global__ __launch_bounds__(64) void k_reduce(const float* __restrict__ ann,
                                               const float* __restrict__ rW,
                                               const float* __restrict__ rb,
                                               float* __restrict__ h0, float* __restrict__ h) {
    int j = threadIdx.x;
    int n0 = blockIdx.x * 16;   // N divisible by 16
    float bias = rb[j];
    float acc[16];
#pragma unroll
    for (int i = 0; i < 16; ++i) acc[i] = bias;
    for (int c = 0; c < 4; ++c) {
        float w[64];
#pragma unroll
        for (int k = 0; k < 64; ++k) w[k] = rW[(c * 64 + k) * 64 + j];  // coalesced across lanes
#pragma unroll
        for (int i = 0; i < 16; ++i) {
            const float* __restrict__ ar = ann + (size_t)(n0 + i) * ASIZE + c * 64;  // uniform -> s_load
#pragma unroll
            for (int k = 0; k < 64; ++k) acc[i] = fmaf(ar[k], w[k], acc[i]);
        }
    }
#pragma unroll
    for (int i = 0; i < 16; ++i) {
        size_t o = (size_t)(n0 + i) * 64 + j;
        h0[o] = acc[i];
        h[o] = acc[i];
    }
}

// ---------------- per-edge-type transform: trans[t][n][:] = h[n] @ eW[t] + eb[t] ----------------
__global__ __launch_bounds__(64) void k_transform(const float* __restrict__ h,
                                                  const float* __restrict__ eW,
                                                  const float* __restrict__ eb,
                                                  float* __restrict__ trans) {
    int j = threadIdx.x;
    int t = blockIdx.y;
    int n0 = blockIdx.x * 64;
    float w[64];
#pragma unroll
    for (int k = 0; k < 64; ++k) w[k] = eW[((t << 6) + k) * 64 + j];  // eW[t][k][j], coalesced
    float bias = eb[(t << 6) + j];
    for (int i = 0; i < 64; ++i) {
        int n = n0 + i;
        if (n >= N_NODES) break;
        const float* __restrict__ hr = h + (size_t)n * 64;  // uniform -> s_load
        float a0 = bias, a1 = 0.f, a2 = 0.f, a3 = 0.f;
#pragma unroll
        for (int k = 0; k < 64; k += 4) {
            a0 = fmaf(hr[k + 0], w[k + 0], a0);
            a1 = fmaf(hr[k + 1], w[k + 1], a1);
            a2 = fmaf(hr[k + 2], w[k + 2], a2);
            a3 = fmaf(hr[k + 3], w[k + 3], a3);
        }
        trans[((size_t)t * N_NODES + n) * 64 + j] = (a0 + a1) + (a2 + a3);
    }
}

// ---------------- edge aggregate: a[n] = sum over incoming edges of trans rows ----------------
__global__ void k_aggregate(const float* __restrict__ trans, const int* __restrict__ rs,
                            const int* __restrict__ colidx, float* __restrict__ a) {
    int l = threadIdx.x & 63;
    int n = blockIdx.x * 4 + (threadIdx.x >> 6);  // 25000 blocks * 4 = N exactly
    int beg = rs[n], end = rs[n + 1];             // wave-uniform
    float acc0 = 0.f, acc1 = 0.f;
    int s = beg;
    for (; s + 1 < end; s += 2) {
        int c0 = colidx[s], c1 = colidx[s + 1];
        acc0 += trans[(size_t)c0 * 64 + l];
        acc1 += trans[(size_t)c1 * 64 + l];
    }
    if (s < end) acc0 += trans[(size_t)colidx[s] * 64 + l];
    a[(size_t)n * 64 + l] = acc0 + acc1;
}

// ---------------- fused GRU cell: h = GRU(a, h), in place ----------------
// one wave, lane j = hidden col; 16 nodes per block; gate-sequential so only 128 W VGPRs live
__global__ __launch_bounds__(64, 1) void k_gru(const float* __restrict__ A, float* __restrict__ H,
                                               const float* __restrict__ WiT,
                                               const float* __restrict__ WhT,
                                               const float* __restrict__ Bi,
                                               const float* __restrict__ Bh) {
    __shared__ float s_rr[16 * 64];
    __shared__ float s_zz[16 * 64];
    int j = threadIdx.x;
    int n0 = blockIdx.x * 16;  // N divisible by 16
    float wi[64], wh[64];

    // ---- gate r
#pragma unroll
    for (int k = 0; k < 64; ++k) { wi[k] = WiT[k * 64 + j]; wh[k] = WhT[k * 64 + j]; }
    float bi = Bi[j], bh = Bh[j];
    for (int i = 0; i < 16; ++i) {
        const float* __restrict__ ar = A + (size_t)(n0 + i) * 64;
        const float* __restrict__ hr = H + (size_t)(n0 + i) * 64;
        float aI0 = bi, aI1 = 0.f, aH0 = bh, aH1 = 0.f;
#pragma unroll
        for (int k = 0; k < 64; k += 2) {
            aI0 = fmaf(ar[k], wi[k], aI0); aI1 = fmaf(ar[k + 1], wi[k + 1], aI1);
            aH0 = fmaf(hr[k], wh[k], aH0); aH1 = fmaf(hr[k + 1], wh[k + 1], aH1);
        }
        s_rr[i * 64 + j] = sigmoidf_((aI0 + aI1) + (aH0 + aH1));
    }
    // ---- gate z
#pragma unroll
    for (int k = 0; k < 64; ++k) { wi[k] = WiT[(64 + k) * 64 + j]; wh[k] = WhT[(64 + k) * 64 + j]; }
    bi = Bi[64 + j]; bh = Bh[64 + j];
    for (int i = 0; i < 16; ++i) {
        const float* __restrict__ ar = A + (size_t)(n0 + i) * 64;
        const float* __restrict__ hr = H + (size_t)(n0 + i) * 64;
        float aI0 = bi, aI1 = 0.f, aH0 = bh, aH1 = 0.f;
#pragma unroll
        for (int k = 0; k < 64; k += 2) {
            aI0 = fmaf(ar[k], wi[k], aI0); aI1 = fmaf(ar[k + 1], wi[k + 1], aI1);
            aH0 = fmaf(hr[k], wh[k], aH0); aH1 = fmaf(hr[k + 1], wh[k + 1], aH1);
        }
        s_zz[i * 64 + j] = sigmoidf_((aI0 + aI1) + (aH0 + aH1));
    }
    // ---- gate n + blend (write h in place; row n never re-read after its write)
#pragma unroll
    for (int k = 0; k < 64; ++k) { wi[k] = WiT[(128 + k) * 64 + j]; wh[k] = WhT[(128 + k) * 64 + j]; }
    bi = Bi[128 + j]; bh = Bh[128 + j];
    for (int i = 0; i < 16; ++i) {
        int n = n0 + i;
        const float* __restrict__ ar = A + (size_t)n * 64;
        const float* __restrict__ hr = H + (size_t)n * 64;
        float aI0 = bi, aI1 = 0.f, aH0 = bh, aH1 = 0.f;
#pragma unroll
        for (int k = 0; k < 64; k += 2) {
            aI0 = fmaf(ar[k], wi[k], aI0); aI1 = fmaf(ar[k + 1], wi[k + 1], aI1);
            aH0 = fmaf(hr[k], wh[k], aH0); aH1 = fmaf(hr[k + 1], wh[k + 1], aH1);
        }
        float in_ = aI0 + aI1, hn = aH0 + aH1;
        float rv = s_rr[i * 64 + j];
        float zv = s_zz[i * 64 + j];
        float nv = tanhf(in_ + rv * hn);
        float hv = H[(size_t)n * 64 + j];
        H[(size_t)n * 64 + j] = (1.0f - zv) * nv + zv * hv;
    }
}

// ---------------- pooling ----------------
static __device__ __forceinline__ unsigned int f2key(float f) {
    unsigned int b = __float_as_uint(f);
    return (b & 0x80000000u) ? ~b : (b | 0x80000000u);
}
static __device__ __forceinline__ float key2f(unsigned int k) {
    unsigned int b = (k & 0x80000000u) ? (k ^ 0x80000000u) : ~k;
    return __uint_as_float(b);
}

__global__ void k_gate(const float* __restrict__ H, const float* __restrict__ H0,
                       const int* __restrict__ gid, const float* __restrict__ gW,
                       const float* __restrict__ gb, float* __restrict__ gate,
                       unsigned int* __restrict__ gmax) {
    int l = threadIdx.x & 63;
    int n = blockIdx.x * 4 + (threadIdx.x >> 6);
    float v = H[(size_t)n * 64 + l] * gW[l] + H0[(size_t)n * 64 + l] * gW[64 + l];
    for (int off = 32; off > 0; off >>= 1) v += __shfl_xor(v, off, 64);
    if (l == 0) {
        float g = v + gb[0];
        gate[n] = g;
        atomicMax(&gmax[gid[n]], f2key(g));
    }
}

__global__ void k_expsum(const float* __restrict__ gate, const int* __restrict__ gid,
                         const unsigned int* __restrict__ gmax, float* __restrict__ ebuf,
                         float* __restrict__ denom) {
    int n = blockIdx.x * 256 + threadIdx.x;
    if (n < N_NODES) {
        int g = gid[n];
        float m = key2f(gmax[g]);
        if (!isfinite(m)) m = 0.0f;  // reference's empty-graph guard
        float e = expf(gate[n] - m);
        ebuf[n] = e;
        atomicAdd(&denom[g], e);
    }
}

__global__ void k_readout(const float* __restrict__ H, const float* __restrict__ H0,
                          const int* __restrict__ gid, const float* __restrict__ ebuf,
                          const float* __restrict__ denom, float* __restrict__ ro) {
    int l = threadIdx.x & 63;
    int n = blockIdx.x * 4 + (threadIdx.x >> 6);
    int g = gid[n];
    float alpha = ebuf[n] / denom[g];
    atomicAdd(&ro[g * 128 + l], alpha * H[(size_t)n * 64 + l]);
    atomicAdd(&ro[g * 128 + 64 + l], alpha * H0[(size_t)n * 64 + l]);
}

__global__ void k_logits(const float* __restrict__ ro, const float* __restrict__ oW,
                         const float* __restrict__ ob, float* __restrict__ out) {
    int t = threadIdx.x;  // 128 threads: (graph, cls)
    int b = t >> 1;
    int c = t & 1;
    float acc = ob[c];
    for (int k = 0; k < 128; ++k) acc = fmaf(ro[b * 128 + k], oW[k * 2 + c], acc);
    out[b * 2 + c] = acc;
}

extern "C" void kernel_launch(void* const* d_in, const int* in_sizes, int n_in,
                              void* d_out, int out_size, void* d_ws, size_t ws_size,
                              hipStream_t stream) {
    (void)in_sizes; (void)n_in; (void)out_size; (void)ws_size;
    const float* ann = (const float*)d_in[0];
    const int* src   = (const int*)d_in[1];
    const int* dst   = (const int*)d_in[2];
    const int* ety   = (const int*)d_in[3];
    const int* gid   = (const int*)d_in[4];
    const float* rW  = (const float*)d_in[5];
    const float* rb  = (const float*)d_in[6];
    const float* eW  = (const float*)d_in[7];
    const float* eb  = (const float*)d_in[8];
    const float* Wi  = (const float*)d_in[9];
    const float* Bi  = (const float*)d_in[10];
    const float* Wh  = (const float*)d_in[11];
    const float* Bh  = (const float*)d_in[12];
    const float* gW  = (const float*)d_in[13];
    const float* gb  = (const float*)d_in[14];
    const float* oW  = (const float*)d_in[15];
    const float* ob  = (const float*)d_in[16];
    float* out = (float*)d_out;

    char* p = (char*)d_ws;
    auto take = [&](size_t nbytes) -> void* {
        void* r = (void*)p;
        p += (nbytes + 255) & ~((size_t)255);
        return r;
    };
    float* h0    = (float*)take((size_t)N_NODES * 64 * 4);
    float* h     = (float*)take((size_t)N_NODES * 64 * 4);
    float* abuf  = (float*)take((size_t)N_NODES * 64 * 4);
    float* trans = (float*)take((size_t)NTYPES * N_NODES * 64 * 4);
    float* WiT   = (float*)take(3 * 64 * 64 * 4);
    float* WhT   = (float*)take(3 * 64 * 64 * 4);
    int* deg     = (int*)take((size_t)N_NODES * 4);
    int* cur     = (int*)take((size_t)N_NODES * 4);
    int* rs      = (int*)take((size_t)(N_NODES + 1) * 4);
    int* part    = (int*)take(512);
    int* colidx  = (int*)take((size_t)N_EDGES * 4);
    float* gate  = (float*)take((size_t)N_NODES * 4);
    float* ebuf  = (float*)take((size_t)N_NODES * 4);
    unsigned int* gmax = (unsigned int*)take(NGRAPH * 4);
    float* denom = (float*)take(NGRAPH * 4);
    float* ro    = (float*)take(NGRAPH * 128 * 4);

    // ---- CSR build
    hipMemsetAsync(deg, 0, (size_t)N_NODES * 4, stream);
    hipMemsetAsync(cur, 0, (size_t)N_NODES * 4, stream);
    k_count<<<(N_EDGES + 255) / 256, 256, 0, stream>>>(dst, deg);
    int nb = (N_NODES + 1023) / 1024;  // 98
    k_scan1<<<nb, 256, 0, stream>>>(deg, rs, part);
    k_scan2<<<1, 64, 0, stream>>>(part, rs, nb);
    k_scan3<<<(N_NODES + 255) / 256, 256, 0, stream>>>(rs, part);
    k_fill<<<(N_EDGES + 255) / 256, 256, 0, stream>>>(src, dst, ety, rs, cur, colidx);

    // ---- weight prep + pooling accumulator init
    k_prepW<<<48, 256, 0, stream>>>(Wi, Wh, WiT, WhT);
    k_init<<<(NGRAPH * 128 + 255) / 256, 256, 0, stream>>>(gmax, denom, ro);

    // ---- reduce layer
    k_reduce<<<N_NODES / 16, 64, 0, stream>>>(ann, rW, rb, h0, h);

    // ---- message-passing steps
    for (int s = 0; s < NSTEPS; ++s) {
        dim3 tg((N_NODES + 63) / 64, NTYPES);
        k_transform<<<tg, 64, 0, stream>>>(h, eW, eb, trans);
        k_aggregate<<<N_NODES / 4, 256, 0, stream>>>(trans, rs, colidx, abuf);
        k_gru<<<N_NODES / 16, 64, 0, stream>>>(abuf, h, WiT, WhT, Bi, Bh);
    }

    // ---- global attention pooling + classifier
    k_gate<<<N_NODES / 4, 256, 0, stream>>>(h, h0, gid, gW, gb, gate, gmax);
    k_expsum<<<(N_NODES + 255) / 256, 256, 0, stream>>>(gate, gid, gmax, ebuf, denom);
    k_readout<<<N_NODES / 4, 256, 0, stream>>>(h, h0, gid, ebuf, denom, ro);
    k_logits<<<1, 128, 0, stream>>>(ro, oW, ob, out);
}

// Round 2
// 4389.970 us; speedup vs baseline: 1.3123x; 1.3123x over previous
//
#include <hip/hip_runtime.h>
#include <cstdint>
#include <cstddef>

#define N_NODES 100000
#define N_EDGES 1200000
#define ASIZE 256
#define HSIZE 64
#define NTYPES 4
#define NSTEPS 6
#define NGRAPH 64

static __device__ __forceinline__ float sigmoidf_(float x) { return 1.0f / (1.0f + expf(-x)); }

// ---------------- CSR build (by dst) ----------------
__global__ void k_count(const int* __restrict__ dst, int* __restrict__ deg) {
    int e = blockIdx.x * 256 + threadIdx.x;
    if (e < N_EDGES) atomicAdd(&deg[dst[e]], 1);
}

// block scans 1024 items (256 thr x 4); writes block-local exclusive prefix + block total
__global__ void k_scan1(const int* __restrict__ deg, int* __restrict__ rs, int* __restrict__ part) {
    __shared__ int sh[256];
    int t = threadIdx.x;
    int base = blockIdx.x * 1024 + t * 4;
    int v0 = (base + 0 < N_NODES) ? deg[base + 0] : 0;
    int v1 = (base + 1 < N_NODES) ? deg[base + 1] : 0;
    int v2 = (base + 2 < N_NODES) ? deg[base + 2] : 0;
    int v3 = (base + 3 < N_NODES) ? deg[base + 3] : 0;
    int s = v0 + v1 + v2 + v3;
    sh[t] = s;
    __syncthreads();
    for (int off = 1; off < 256; off <<= 1) {
        int x = (t >= off) ? sh[t - off] : 0;
        __syncthreads();
        sh[t] += x;
        __syncthreads();
    }
    int excl = sh[t] - s;  // block-local exclusive at this thread's start
    if (t == 255) part[blockIdx.x] = sh[255];
    if (base + 0 < N_NODES) rs[base + 0] = excl;
    if (base + 1 < N_NODES) rs[base + 1] = excl + v0;
    if (base + 2 < N_NODES) rs[base + 2] = excl + v0 + v1;
    if (base + 3 < N_NODES) rs[base + 3] = excl + v0 + v1 + v2;
}

__global__ void k_scan2(int* __restrict__ part, int* __restrict__ rs, int nb) {
    if (threadIdx.x == 0 && blockIdx.x == 0) {
        int run = 0;
        for (int i = 0; i < nb; ++i) { int v = part[i]; part[i] = run; run += v; }
        rs[N_NODES] = run;   // == N_EDGES
    }
}

__global__ void k_scan3(int* __restrict__ rs, const int* __restrict__ part) {
    int i = blockIdx.x * 256 + threadIdx.x;
    if (i < N_NODES) rs[i] += part[i >> 10];
}

__global__ void k_fill(const int* __restrict__ src, const int* __restrict__ dst,
                       const int* __restrict__ ety, const int* __restrict__ rs,
                       int* __restrict__ cur, int* __restrict__ colidx) {
    int e = blockIdx.x * 256 + threadIdx.x;
    if (e < N_EDGES) {
        int d = dst[e];
        int pos = rs[d] + atomicAdd(&cur[d], 1);
        colidx[pos] = ety[e] * N_NODES + src[e];  // row index into trans
    }
}

// ---------------- weight prep: transpose GRU weights to [gate][k][j] ----------------
__global__ void k_prepW(const float* __restrict__ Wi, const float* __restrict__ Wh,
                        float* __restrict__ WiT, float* __restrict__ WhT) {
    int i = blockIdx.x * 256 + threadIdx.x;  // over 3*64*64
    if (i < 3 * 64 * 64) {
        int g = i >> 12;
        int k = (i >> 6) & 63;
        int j = i & 63;
        WiT[i] = Wi[(g * 64 + j) * 64 + k];
        WhT[i] = Wh[(g * 64 + j) * 64 + k];
    }
}

// ---------------- reduce layer: h0 = ann @ rW + rb ; h = h0 ----------------
__global__ __launch_bounds__(64) void k_reduce(const float* __restrict__ ann,
                                               const float* __restrict__ rW,
                                               const float* __restrict__ rb,
                                               float* __restrict__ h0, float* __restrict__ h) {
    int j = threadIdx.x;
    int n0 = blockIdx.x * 16;   // N divisible by 16
    float bias = rb[j];
    float acc[16];
#pragma unroll
    for (int i = 0; i < 16; ++i) acc[i] = bias;
    for (int c = 0; c < 4; ++c) {
        float w[64];
#pragma unroll
        for (int k = 0; k < 64; ++k) w[k] = rW[(c * 64 + k) * 64 + j];  // coalesced across lanes
#pragma unroll
        for (int i = 0; i < 16; ++i) {
            const float* __restrict__ ar = ann + (size_t)(n0 + i) * ASIZE + c * 64;  // uniform -> s_load
#pragma unroll
            for (int k = 0; k < 64; ++k) acc[i] = fmaf(ar[k], w[k], acc[i]);
        }
    }
#pragma unroll
    for (int i = 0; i < 16; ++i) {
        size_t o = (size_t)(n0 + i) * 64 + j;
        h0[o] = acc[i];
        h[o] = acc[i];
    }
}

// ---------------- per-edge-type transform: trans[t][n][:] = h[n] @ eW[t] + eb[t] ----------------
__global__ __launch_bounds__(64) void k_transform(const float* __restrict__ h,
                                                  const float* __restrict__ eW,
                                                  const float* __restrict__ eb,
                                                  float* __restrict__ trans) {
    int j = threadIdx.x;
    int t = blockIdx.y;
    int n0 = blockIdx.x * 64;
    float w[64];
#pragma unroll
    for (int k = 0; k < 64; ++k) w[k] = eW[((t << 6) + k) * 64 + j];  // eW[t][k][j], coalesced
    float bias = eb[(t << 6) + j];
    for (int i = 0; i < 64; ++i) {
        int n = n0 + i;
        if (n >= N_NODES) break;
        const float* __restrict__ hr = h + (size_t)n * 64;  // uniform -> s_load
        float a0 = bias, a1 = 0.f, a2 = 0.f, a3 = 0.f;
#pragma unroll
        for (int k = 0; k < 64; k += 4) {
            a0 = fmaf(hr[k + 0], w[k + 0], a0);
            a1 = fmaf(hr[k + 1], w[k + 1], a1);
            a2 = fmaf(hr[k + 2], w[k + 2], a2);
            a3 = fmaf(hr[k + 3], w[k + 3], a3);
        }
        trans[((size_t)t * N_NODES + n) * 64 + j] = (a0 + a1) + (a2 + a3);
    }
}

// ---------------- edge aggregate: a[n] = sum over incoming edges of trans rows ----------------
__global__ void k_aggregate(const float* __restrict__ trans, const int* __restrict__ rs,
                            const int* __restrict__ colidx, float* __restrict__ a) {
    int l = threadIdx.x & 63;
    int n = blockIdx.x * 4 + (threadIdx.x >> 6);  // 25000 blocks * 4 = N exactly
    int beg = rs[n], end = rs[n + 1];             // wave-uniform
    float acc0 = 0.f, acc1 = 0.f;
    int s = beg;
    for (; s + 1 < end; s += 2) {
        int c0 = colidx[s], c1 = colidx[s + 1];
        acc0 += trans[(size_t)c0 * 64 + l];
        acc1 += trans[(size_t)c1 * 64 + l];
    }
    if (s < end) acc0 += trans[(size_t)colidx[s] * 64 + l];
    a[(size_t)n * 64 + l] = acc0 + acc1;
}

// ---------------- fused GRU cell: h = GRU(a, h), in place ----------------
__global__ __launch_bounds__(64, 1) void k_gru(const float* __restrict__ A, float* __restrict__ H,
                                               const float* __restrict__ WiT,
                                               const float* __restrict__ WhT,
                                               const float* __restrict__ Bi,
                                               const float* __restrict__ Bh) {
    __shared__ float s_rr[16 * 64];
    __shared__ float s_zz[16 * 64];
    int j = threadIdx.x;
    int n0 = blockIdx.x * 16;  // N divisible by 16
    float wi[64], wh[64];

    // ---- gate r
#pragma unroll
    for (int k = 0; k < 64; ++k) { wi[k] = WiT[k * 64 + j]; wh[k] = WhT[k * 64 + j]; }
    float bi = Bi[j], bh = Bh[j];
    for (int i = 0; i < 16; ++i) {
        const float* __restrict__ ar = A + (size_t)(n0 + i) * 64;
        const float* __restrict__ hr = H + (size_t)(n0 + i) * 64;
        float aI0 = bi, aI1 = 0.f, aH0 = bh, aH1 = 0.f;
#pragma unroll
        for (int k = 0; k < 64; k += 2) {
            aI0 = fmaf(ar[k], wi[k], aI0); aI1 = fmaf(ar[k + 1], wi[k + 1], aI1);
            aH0 = fmaf(hr[k], wh[k], aH0); aH1 = fmaf(hr[k + 1], wh[k + 1], aH1);
        }
        s_rr[i * 64 + j] = sigmoidf_((aI0 + aI1) + (aH0 + aH1));
    }
    // ---- gate z
#pragma unroll
    for (int k = 0; k < 64; ++k) { wi[k] = WiT[(64 + k) * 64 + j]; wh[k] = WhT[(64 + k) * 64 + j]; }
    bi = Bi[64 + j]; bh = Bh[64 + j];
    for (int i = 0; i < 16; ++i) {
        const float* __restrict__ ar = A + (size_t)(n0 + i) * 64;
        const float* __restrict__ hr = H + (size_t)(n0 + i) * 64;
        float aI0 = bi, aI1 = 0.f, aH0 = bh, aH1 = 0.f;
#pragma unroll
        for (int k = 0; k < 64; k += 2) {
            aI0 = fmaf(ar[k], wi[k], aI0); aI1 = fmaf(ar[k + 1], wi[k + 1], aI1);
            aH0 = fmaf(hr[k], wh[k], aH0); aH1 = fmaf(hr[k + 1], wh[k + 1], aH1);
        }
        s_zz[i * 64 + j] = sigmoidf_((aI0 + aI1) + (aH0 + aH1));
    }
    // ---- gate n + blend
#pragma unroll
    for (int k = 0; k < 64; ++k) { wi[k] = WiT[(128 + k) * 64 + j]; wh[k] = WhT[(128 + k) * 64 + j]; }
    bi = Bi[128 + j]; bh = Bh[128 + j];
    for (int i = 0; i < 16; ++i) {
        int n = n0 + i;
        const float* __restrict__ ar = A + (size_t)n * 64;
        const float* __restrict__ hr = H + (size_t)n * 64;
        float aI0 = bi, aI1 = 0.f, aH0 = bh, aH1 = 0.f;
#pragma unroll
        for (int k = 0; k < 64; k += 2) {
            aI0 = fmaf(ar[k], wi[k], aI0); aI1 = fmaf(ar[k + 1], wi[k + 1], aI1);
            aH0 = fmaf(hr[k], wh[k], aH0); aH1 = fmaf(hr[k + 1], wh[k + 1], aH1);
        }
        float in_ = aI0 + aI1, hn = aH0 + aH1;
        float rv = s_rr[i * 64 + j];
        float zv = s_zz[i * 64 + j];
        float nv = tanhf(in_ + rv * hn);
        float hv = H[(size_t)n * 64 + j];
        H[(size_t)n * 64 + j] = (1.0f - zv) * nv + zv * hv;
    }
}

// ---------------- pooling: segmented, atomic-free (gid is sorted) ----------------
// start[g] = first node of graph g; start[NGRAPH] = N
__global__ void k_bounds(const int* __restrict__ gid, int* __restrict__ start) {
    int n = blockIdx.x * 256 + threadIdx.x;
    if (n < N_NODES) {
        int g = gid[n];
        if (n == 0) {
            for (int x = 0; x <= g; ++x) start[x] = 0;
        } else {
            int pg = gid[n - 1];
            for (int x = pg + 1; x <= g; ++x) start[x] = n;
        }
        if (n == N_NODES - 1) {
            for (int x = g + 1; x <= NGRAPH; ++x) start[x] = N_NODES;
        }
    }
}

// gate[n] = feat[n] . gate_W + gate_b  (wave per 4 nodes, shuffle-reduce)
__global__ void k_gate2(const float* __restrict__ H, const float* __restrict__ H0,
                        const float* __restrict__ gW, const float* __restrict__ gb,
                        float* __restrict__ gate) {
    int l = threadIdx.x & 63;
    int n = blockIdx.x * 4 + (threadIdx.x >> 6);
    float v = H[(size_t)n * 64 + l] * gW[l] + H0[(size_t)n * 64 + l] * gW[64 + l];
    for (int off = 32; off > 0; off >>= 1) v += __shfl_xor(v, off, 64);
    if (l == 0) gate[n] = v + gb[0];
}

// one block per graph: max -> exp-sum -> weighted readout, all in-block
__global__ __launch_bounds__(256) void k_pool(const float* __restrict__ H,
                                              const float* __restrict__ H0,
                                              const float* __restrict__ gate,
                                              const int* __restrict__ start,
                                              float* __restrict__ ro) {
    int g = blockIdx.x;
    int beg = start[g], end = start[g + 1];
    int t = threadIdx.x;
    int lane = t & 63, wave = t >> 6;
    __shared__ float sred[256];
    __shared__ float shh[4][64], sh0[4][64];

    // --- segment max
    float m = -INFINITY;
    for (int n = beg + t; n < end; n += 256) m = fmaxf(m, gate[n]);
    sred[t] = m; __syncthreads();
    for (int off = 128; off > 0; off >>= 1) {
        if (t < off) sred[t] = fmaxf(sred[t], sred[t + off]);
        __syncthreads();
    }
    m = sred[0];
    if (!isfinite(m)) m = 0.0f;  // reference's empty-graph guard
    __syncthreads();

    // --- sum of exp
    float s = 0.f;
    for (int n = beg + t; n < end; n += 256) s += expf(gate[n] - m);
    sred[t] = s; __syncthreads();
    for (int off = 128; off > 0; off >>= 1) {
        if (t < off) sred[t] += sred[t + off];
        __syncthreads();
    }
    float inv_denom = 1.0f / sred[0];
    __syncthreads();

    // --- weighted readout: wave w strides nodes, lane = column
    float ah = 0.f, ah0 = 0.f;
    for (int n = beg + wave; n < end; n += 4) {
        float alpha = expf(gate[n] - m) * inv_denom;   // gate[n] wave-uniform -> s_load
        ah  += alpha * H [(size_t)n * 64 + lane];
        ah0 += alpha * H0[(size_t)n * 64 + lane];
    }
    shh[wave][lane] = ah; sh0[wave][lane] = ah0;
    __syncthreads();
    if (wave == 0) {
        float r  = shh[0][lane] + shh[1][lane] + shh[2][lane] + shh[3][lane];
        float r0 = sh0[0][lane] + sh0[1][lane] + sh0[2][lane] + sh0[3][lane];
        ro[g * 128 + lane]      = r;
        ro[g * 128 + 64 + lane] = r0;
    }
}

__global__ void k_logits(const float* __restrict__ ro, const float* __restrict__ oW,
                         const float* __restrict__ ob, float* __restrict__ out) {
    int t = threadIdx.x;  // 128 threads: (graph, cls)
    int b = t >> 1;
    int c = t & 1;
    float acc = ob[c];
    for (int k = 0; k < 128; ++k) acc = fmaf(ro[b * 128 + k], oW[k * 2 + c], acc);
    out[b * 2 + c] = acc;
}

extern "C" void kernel_launch(void* const* d_in, const int* in_sizes, int n_in,
                              void* d_out, int out_size, void* d_ws, size_t ws_size,
                              hipStream_t stream) {
    (void)in_sizes; (void)n_in; (void)out_size; (void)ws_size;
    const float* ann = (const float*)d_in[0];
    const int* src   = (const int*)d_in[1];
    const int* dst   = (const int*)d_in[2];
    const int* ety   = (const int*)d_in[3];
    const int* gid   = (const int*)d_in[4];
    const float* rW  = (const float*)d_in[5];
    const float* rb  = (const float*)d_in[6];
    const float* eW  = (const float*)d_in[7];
    const float* eb  = (const float*)d_in[8];
    const float* Wi  = (const float*)d_in[9];
    const float* Bi  = (const float*)d_in[10];
    const float* Wh  = (const float*)d_in[11];
    const float* Bh  = (const float*)d_in[12];
    const float* gW  = (const float*)d_in[13];
    const float* gb  = (const float*)d_in[14];
    const float* oW  = (const float*)d_in[15];
    const float* ob  = (const float*)d_in[16];
    float* out = (float*)d_out;

    char* p = (char*)d_ws;
    auto take = [&](size_t nbytes) -> void* {
        void* r = (void*)p;
        p += (nbytes + 255) & ~((size_t)255);
        return r;
    };
    float* h0    = (float*)take((size_t)N_NODES * 64 * 4);
    float* h     = (float*)take((size_t)N_NODES * 64 * 4);
    float* abuf  = (float*)take((size_t)N_NODES * 64 * 4);
    float* trans = (float*)take((size_t)NTYPES * N_NODES * 64 * 4);
    float* WiT   = (float*)take(3 * 64 * 64 * 4);
    float* WhT   = (float*)take(3 * 64 * 64 * 4);
    int* deg     = (int*)take((size_t)N_NODES * 4);
    int* cur     = (int*)take((size_t)N_NODES * 4);
    int* rs      = (int*)take((size_t)(N_NODES + 1) * 4);
    int* part    = (int*)take(512);
    int* colidx  = (int*)take((size_t)N_EDGES * 4);
    float* gate  = (float*)take((size_t)N_NODES * 4);
    int* start   = (int*)take((size_t)(NGRAPH + 1) * 4);
    float* ro    = (float*)take(NGRAPH * 128 * 4);

    // ---- CSR build
    hipMemsetAsync(deg, 0, (size_t)N_NODES * 4, stream);
    hipMemsetAsync(cur, 0, (size_t)N_NODES * 4, stream);
    k_count<<<(N_EDGES + 255) / 256, 256, 0, stream>>>(dst, deg);
    int nb = (N_NODES + 1023) / 1024;  // 98
    k_scan1<<<nb, 256, 0, stream>>>(deg, rs, part);
    k_scan2<<<1, 64, 0, stream>>>(part, rs, nb);
    k_scan3<<<(N_NODES + 255) / 256, 256, 0, stream>>>(rs, part);
    k_fill<<<(N_EDGES + 255) / 256, 256, 0, stream>>>(src, dst, ety, rs, cur, colidx);

    // ---- weight prep + graph bounds
    k_prepW<<<48, 256, 0, stream>>>(Wi, Wh, WiT, WhT);
    k_bounds<<<(N_NODES + 255) / 256, 256, 0, stream>>>(gid, start);

    // ---- reduce layer
    k_reduce<<<N_NODES / 16, 64, 0, stream>>>(ann, rW, rb, h0, h);

    // ---- message-passing steps
    for (int s = 0; s < NSTEPS; ++s) {
        dim3 tg((N_NODES + 63) / 64, NTYPES);
        k_transform<<<tg, 64, 0, stream>>>(h, eW, eb, trans);
        k_aggregate<<<N_NODES / 4, 256, 0, stream>>>(trans, rs, colidx, abuf);
        k_gru<<<N_NODES / 16, 64, 0, stream>>>(abuf, h, WiT, WhT, Bi, Bh);
    }

    // ---- global attention pooling + classifier (atomic-free)
    k_gate2<<<N_NODES / 4, 256, 0, stream>>>(h, h0, gW, gb, gate);
    k_pool<<<NGRAPH, 256, 0, stream>>>(h, h0, gate, start, ro);
    k_logits<<<1, 128, 0, stream>>>(ro, oW, ob, out);
}